// Round 6
// baseline (141.633 us; speedup 1.0000x reference)
//
#include <hip/hip_runtime.h>

// Problem constants (match reference)
constexpr int T     = 4;
constexpr int NROWS = 1000000;
constexpr int B     = 16384;
constexpr int TOTAL = 16384 * 50; // 819200 lookups per table

typedef float    fv4 __attribute__((ext_vector_type(4)));
typedef int      iv2 __attribute__((ext_vector_type(2)));
typedef _Float16 h2  __attribute__((ext_vector_type(2)));

// ws layout: p[T*NROWS] _Float16 (8 MB).

// ============================ DIAGNOSTIC ROUND ============================
// r0/r3/r5 all land at ~133.5-134.6 total; produce+pool busy ≈ 44.6 µs vs a
// ~23 µs BW model, and NEITHER kernel has ever crossed the top-5 visibility
// cutoff (~40 µs), so the 20 µs residual is unattributed. This round runs
// produce TWICE (pass 2 rotated by half the pair space, writing identical
// values — bitwise idempotent, results unchanged) to (a) push the produce
// dispatch above the cutoff if produce is the hog, exposing its counters,
// and (b) measure produce_busy = Δtotal vs r5 either way.
// Pool is EXACTLY r5 for clean interpretation.
// =========================================================================

// Producer: p[t*NROWS+r] = dot(table[t][r], W), 2 rows/thread, fp16 pack.
// Two grid-strided passes; pass 2 covers pair-index (i + 1e6) mod 2e6 so it
// re-walks the whole table from a different block->address mapping (defeats
// own-L1/L2 reuse; at worst L3-assisted, giving a lower bound on produce).
__global__ __launch_bounds__(256)
void produce_kernel(const fv4*   __restrict__ tables,
                    const float* __restrict__ Wp,
                    const float* __restrict__ bias,
                    h2*          __restrict__ p2,     // [T*NROWS/2]
                    float*       __restrict__ out) {
    const int NP = T * NROWS / 2;                     // 2,000,000 pairs
    const int i0 = blockIdx.x * 256 + threadIdx.x;
    const float wx = Wp[0], wy = Wp[1], wz = Wp[2], ww = Wp[3];

    #pragma unroll 1
    for (int pass = 0; pass < 2; ++pass) {
        if (i0 < NP) {
            int i = i0 + pass * (NP / 2);             // rotate half-space on pass 2
            if (i >= NP) i -= NP;
            const fv4 a = tables[2 * i];              // two independent loads
            const fv4 b = tables[2 * i + 1];
            const float pa = a.x * wx + a.y * wy + a.z * wz + a.w * ww;
            const float pb = b.x * wx + b.y * wy + b.z * wz + b.w * ww;
            h2 h; h.x = (_Float16)pa; h.y = (_Float16)pb;
            p2[i] = h;                                // identical value both passes
        }
    }
    if (i0 < T * B) out[i0] = bias[0];                // fused bias init
}

// Pool — EXACTLY r5 (fp16 gathers, 2 lookups/thread, segmented wave scan,
// XCD-pinned table->XCD-pair mapping, NT stream loads).
__global__ __launch_bounds__(256)
void pool_kernel(const _Float16* __restrict__ p,       // [T*NROWS] fp16
                 const iv2*      __restrict__ indices, // [T*TOTAL/2]
                 const iv2*      __restrict__ segids,  // [T*TOTAL/2] sorted/table
                 float*          __restrict__ out)     // [T*B], pre-set to bias
{
    const int xcd    = blockIdx.x & 7;
    const int t      = xcd >> 1;
    const int within = ((blockIdx.x >> 3) << 1) + (xcd & 1);   // [0, 1600)
    const int q      = within * 256 + threadIdx.x;
    const int gq     = t * (TOTAL / 2) + q;
    const int lane   = threadIdx.x & 63;

    const iv2 s2 = __builtin_nontemporal_load(&segids[gq]);
    const iv2 i2 = __builtin_nontemporal_load(&indices[gq]);

    const _Float16* pt = p + t * NROWS;
    const float v0 = (float)pt[i2.x];
    const float v1 = (float)pt[i2.y];
    const int   s0 = s2.x, s1 = s2.y;

    const float a0 = v0;
    const float a1 = v1 + (s1 == s0 ? v0 : 0.f);

    float x   = a1;
    int   key = s1;
    #pragma unroll
    for (int d = 1; d < 64; d <<= 1) {
        const float ov = __shfl_up(x, d, 64);
        const int   ok = __shfl_up(key, d, 64);
        if (lane >= d && ok == key) x += ov;
    }

    const float xprev = __shfl_up(x, 1, 64);
    const int   kprev = __shfl_up(key, 1, 64);
    const float carry = (lane > 0 && kprev == s0) ? xprev : 0.f;

    float* outt = out + t * B;
    if (s0 != s1) atomicAdd(&outt[s0], a0 + carry);

    const int snext = __shfl_down(s0, 1, 64);
    if (lane == 63 || snext != key) atomicAdd(&outt[key], x);
}

extern "C" void kernel_launch(void* const* d_in, const int* in_sizes, int n_in,
                              void* d_out, int out_size, void* d_ws, size_t ws_size,
                              hipStream_t stream) {
    const fv4*   tables  = (const fv4*)d_in[0];      // [T, N, 4] f32
    const float* W       = (const float*)d_in[1];    // [1, 4]   f32
    const float* bias    = (const float*)d_in[2];    // [1]      f32
    const iv2*   indices = (const iv2*)d_in[3];      // [T, TOTAL]
    const iv2*   segids  = (const iv2*)d_in[4];      // [T, TOTAL] sorted per table
    float*       out     = (float*)d_out;            // [T*B] f32

    h2*       p2 = (h2*)d_ws;                        // 8 MB fp16 scratch
    _Float16* p  = (_Float16*)d_ws;

    {
        int n = T * NROWS / 2;                       // 2,000,000 pairs -> 7813 blocks
        produce_kernel<<<(n + 255) / 256, 256, 0, stream>>>(tables, W, bias, p2, out);
    }
    {
        pool_kernel<<<6400, 256, 0, stream>>>(p, indices, segids, out);
    }
}

// Round 7
// 128.947 us; speedup vs baseline: 1.0984x; 1.0984x over previous
//
#include <hip/hip_runtime.h>

// Problem constants (match reference)
constexpr int T     = 4;
constexpr int NROWS = 1000000;
constexpr int B     = 16384;
constexpr int TOTAL = 16384 * 50; // 819200 lookups per table

typedef float    fv4 __attribute__((ext_vector_type(4)));
typedef int      iv2 __attribute__((ext_vector_type(2)));
typedef _Float16 h2  __attribute__((ext_vector_type(2)));

// ws layout: p[T*NROWS] _Float16 (8 MB). fp16 quantization err accumulates to
// ~3.5e-5 << the ~1e-3 tolerance already measured passing (r5/r6).

// Producer (r5 proven, ~7-12 us ≈ BW floor per r6's double-pass diagnostic):
// p[t*NROWS+r] = dot(table[t][r], W), 2 rows/thread, packed h2 store.
// Cached table loads (r1: NT table loads regress). Fused out[:] = bias init.
__global__ __launch_bounds__(256)
void produce_kernel(const fv4*   __restrict__ tables,
                    const float* __restrict__ Wp,
                    const float* __restrict__ bias,
                    h2*          __restrict__ p2,     // [T*NROWS/2]
                    float*       __restrict__ out) {
    const int i = blockIdx.x * 256 + threadIdx.x;     // pair index [0, 2M)
    if (i < T * NROWS / 2) {
        const float wx = Wp[0], wy = Wp[1], wz = Wp[2], ww = Wp[3];
        const fv4 a = tables[2 * i];
        const fv4 b = tables[2 * i + 1];
        const float pa = a.x * wx + a.y * wy + a.z * wz + a.w * ww;
        const float pb = b.x * wx + b.y * wy + b.z * wz + b.w * ww;
        h2 h; h.x = (_Float16)pa; h.y = (_Float16)pb;
        p2[i] = h;
    }
    if (i < T * B) out[i] = bias[0];
}

// --- wave64 inclusive +scan via DPP (classic GCN idiom): 6 VALU ops, no LDS.
template<int CTRL, int ROW_MASK, int BANK_MASK>
__device__ __forceinline__ float dpp_add(float x) {
    const int t = __builtin_amdgcn_update_dpp(0, __float_as_int(x),
                                              CTRL, ROW_MASK, BANK_MASK, true);
    return x + __int_as_float(t);
}
__device__ __forceinline__ float wave64_incl_scan(float x) {
    x = dpp_add<0x111, 0xf, 0xf>(x);   // row_shr:1  (within 16-lane rows)
    x = dpp_add<0x112, 0xf, 0xf>(x);   // row_shr:2
    x = dpp_add<0x114, 0xf, 0xf>(x);   // row_shr:4
    x = dpp_add<0x118, 0xf, 0xf>(x);   // row_shr:8
    x = dpp_add<0x142, 0xa, 0xf>(x);   // row_bcast:15 -> rows 1,3
    x = dpp_add<0x143, 0xc, 0xf>(x);   // row_bcast:31 -> rows 2,3
    return x;                          // P[lane] = sum_{i<=lane} x_i
}

// Pool, r6 diagnostic-driven rewrite. Was ~28 us vs a ~9 us traffic model:
// latency-bound on {NT stream load -> gather -> 12 serially-dependent
// ds_bpermute shfls}. Fixes:
//  (a) cached idx/seg loads (inputs are L3-warm from the restore; NT bypassed
//      the cache and put ~900cy HBM latency at the head of the chain — same
//      lesson as r1's NT-table regression);
//  (b) segmented scan -> unsegmented DPP scan (pure VALU) + algebraic
//      segmentation: run sums as prefix differences, run starts from
//      ballot(head-flags). Only 4 bpermutes remain, none serially chained.
// Keeps: 2 lookups/thread (fp16 gathers, 2x MLP), XCD pinning (table t ->
// XCD pair {2t,2t+1}; 2 MB fp16 p slice resident in 4 MB L2).
__global__ __launch_bounds__(256)
void pool_kernel(const _Float16* __restrict__ p,       // [T*NROWS] fp16
                 const iv2*      __restrict__ indices, // [T*TOTAL/2]
                 const iv2*      __restrict__ segids,  // [T*TOTAL/2] sorted/table
                 float*          __restrict__ out)     // [T*B], pre-set to bias
{
    const int xcd    = blockIdx.x & 7;
    const int t      = xcd >> 1;
    const int within = ((blockIdx.x >> 3) << 1) + (xcd & 1);   // [0, 1600)
    const int q      = within * 256 + threadIdx.x;             // pair idx
    const int gq     = t * (TOTAL / 2) + q;
    const int lane   = threadIdx.x & 63;

    const iv2 s2 = segids[gq];          // cached: L3-warm from restore
    const iv2 i2 = indices[gq];

    const _Float16* pt = p + t * NROWS;
    const float v0 = (float)pt[i2.x];   // two independent gathers (MLP)
    const float v1 = (float)pt[i2.y];
    const int   s0 = s2.x, s1 = s2.y;

    // In-lane pair combine: x = sum of this lane's elements in its TAIL run.
    const float a0 = v0;
    const float x  = v1 + (s1 == s0 ? v0 : 0.f);
    const int   key = s1;

    // Unsegmented inclusive scan P, exclusive E = P - x (pure VALU).
    const float P = wave64_incl_scan(x);
    const float E = P - x;              // = P[lane-1]

    // Head flags over tail-keys. Sorted segs => equal keys contiguous; an
    // internal-boundary lane (s0!=s1) always starts a new key run (sortedness
    // forbids kprev==s1 when s0!=s1), so heads are exactly kprev!=key.
    const int kprev = __shfl_up(key, 1, 64);
    const int snext = __shfl_down(s0, 1, 64);
    const bool head = (lane == 0) || (kprev != key);
    const unsigned long long mask = __ballot(head);

    // F  = start lane of MY tail-key run (highest head <= lane).
    const unsigned long long le = mask & (~0ULL >> (63 - lane));
    const int   F  = 63 - __builtin_clzll(le);
    const float Ef = __shfl(E, F, 64);                 // P[F-1]

    // F' = start lane of the run ending at lane-1 (for the internal carry).
    const unsigned long long lt = lane ? (mask & (~0ULL >> (64 - lane))) : 1ULL;
    const int   Fp  = 63 - __builtin_clzll(lt);
    const float Efp = __shfl(E, Fp, 64);               // P[F'-1]

    float* outt = out + t * B;

    // Internal-boundary flush: seg s0 ends at this lane's element 0. Its sum =
    // a0 + (tail-run contributions of lanes [F', lane-1] if they carry key s0).
    if (s0 != s1) {
        const float carry = (lane > 0 && kprev == s0) ? (E - Efp) : 0.f;
        atomicAdd(&outt[s0], a0 + carry);
    }

    // Tail flush: last lane of each tail-key run; run sum = P - P[F-1].
    if (lane == 63 || snext != key) {
        atomicAdd(&outt[key], P - Ef);
    }
}

extern "C" void kernel_launch(void* const* d_in, const int* in_sizes, int n_in,
                              void* d_out, int out_size, void* d_ws, size_t ws_size,
                              hipStream_t stream) {
    const fv4*   tables  = (const fv4*)d_in[0];      // [T, N, 4] f32
    const float* W       = (const float*)d_in[1];    // [1, 4]   f32
    const float* bias    = (const float*)d_in[2];    // [1]      f32
    const iv2*   indices = (const iv2*)d_in[3];      // [T, TOTAL]
    const iv2*   segids  = (const iv2*)d_in[4];      // [T, TOTAL] sorted per table
    float*       out     = (float*)d_out;            // [T*B] f32

    h2*       p2 = (h2*)d_ws;                        // 8 MB fp16 scratch
    _Float16* p  = (_Float16*)d_ws;

    {
        int n = T * NROWS / 2;                       // 2,000,000 pairs -> 7813 blocks
        produce_kernel<<<(n + 255) / 256, 256, 0, stream>>>(tables, W, bias, p2, out);
    }
    {
        // T*TOTAL/2 = 1,638,400 threads = 6,400 blocks (multiple of 8 for pinning)
        pool_kernel<<<6400, 256, 0, stream>>>(p, indices, segids, out);
    }
}